// Round 7
// baseline (8958.540 us; speedup 1.0000x reference)
//
#include <hip/hip_runtime.h>

// ---------------------------------------------------------------------------
// 2-layer LSTM (B=256,T=512,H=512,DIN=64) + FC, persistent-kernel wavefront.
// R7: R4 skeleton (plain L2-served h loads + 1 acquire-inv per step, proven
// fastest) + deep load pipelining: all step loads issued up-front into fully
// unrolled register arrays (32-64 in flight, compiler emits progressive
// vmcnt) instead of PREF=4 rotation (8 in flight -> ~3us exposed LLC latency).
// Gates are per-wave (no barrier between gate and loads); partner/WAR gates
// first, critical own-gate last; publish is a relaxed sc1 store.
// KEY lesson from R5/R6: sc1 LLC-direct data reads are BW-infeasible (32-way
// slab broadcast -> 8-13 MB/step over the ~1TB/s XCD<->LLC link); the XCD L2
// must serve the broadcast -> plain loads + per-step inv.
// ---------------------------------------------------------------------------

typedef _Float16 f16;
typedef _Float16 f16x8 __attribute__((ext_vector_type(8)));
typedef float    f32x4 __attribute__((ext_vector_type(4)));
typedef unsigned long long u64;

constexpr int NB   = 256;   // batch
constexpr int NT   = 512;   // time steps
constexpr int NH   = 512;   // hidden
constexpr int NDIN = 64;    // input dim

constexpr int L0_KC = 18;   // K chunks of 32: 64(x) + 512(h0) = 576
constexpr int L1_KC = 32;   // 512(h0) + 512(h1) = 1024
constexpr int L0_IMG_HALVES = 4 * L0_KC * 64 * 8;  // 73728 B per htile
constexpr int L1_IMG_HALVES = 4 * L1_KC * 64 * 8;  // 131072 B per htile

// ws layout (bytes), all 256-aligned (identical footprint to R4)
constexpr size_t BAR_OFF   = 0;                        // flag lines: 8 groups * 128 B
constexpr size_t BIAS0_OFF = 8192;                     // 2048 f32
constexpr size_t BIAS1_OFF = 16384;                    // 2048 f32
constexpr size_t H0R_OFF   = 24576;                    // [4][256][512] f16 = 1 MB
constexpr size_t H1R_OFF   = H0R_OFF + 1048576;        // [2][256][512] f16 = 512 KB
constexpr size_t XT_OFF    = H1R_OFF + 524288;         // [512][256][64] f16
constexpr size_t W0I_OFF   = XT_OFF + 16777216;        // 32 htiles * 73728 B
constexpr size_t W1I_OFF   = W0I_OFF + 2359296;        // 32 htiles * 131072 B
constexpr size_t WS_NEED   = W1I_OFF + 4194304;        // ~23.8 MB

// ---------------------------------------------------------------------------
// Prep: swizzle weights (fp32 -> fp16) into MFMA B-fragment order.
// B-frag layout (16x16x32): lane L holds B[k = (L>>4)*8 + j][n = L&15], j=0..7
// Image element order: [htile][nf(=gate)][kc][lane][8 halves]
// ---------------------------------------------------------------------------
__global__ void prep_weights(const float* __restrict__ Wih0, const float* __restrict__ Whh0,
                             const float* __restrict__ Wih1, const float* __restrict__ Whh1,
                             char* __restrict__ ws) {
    int idx = blockIdx.x * 256 + threadIdx.x;
    const int L0_CH = 32 * 4 * L0_KC * 64;   // 147456
    const int L1_CH = 32 * 4 * L1_KC * 64;   // 262144
    if (idx < L0_CH) {
        int lam = idx & 63;
        int kc  = (idx >> 6) % L0_KC;
        int nf  = ((idx >> 6) / L0_KC) & 3;
        int ht  = idx / (64 * L0_KC * 4);
        int g   = nf * NH + ht * 16 + (lam & 15);   // gate row in [0,2048)
        int kb  = kc * 32 + (lam >> 4) * 8;
        f16x8 v;
#pragma unroll
        for (int j = 0; j < 8; ++j) {
            int k = kb + j;
            float val = (k < NDIN) ? Wih0[(size_t)g * NDIN + k]
                                   : Whh0[(size_t)g * NH + (k - NDIN)];
            v[j] = (f16)val;
        }
        f16* dst = (f16*)(ws + W0I_OFF) + (size_t)ht * L0_IMG_HALVES
                 + ((size_t)(nf * L0_KC + kc) * 64 + lam) * 8;
        *(f16x8*)dst = v;
    } else if (idx < L0_CH + L1_CH) {
        int i2  = idx - L0_CH;
        int lam = i2 & 63;
        int kc  = (i2 >> 6) % L1_KC;
        int nf  = ((i2 >> 6) / L1_KC) & 3;
        int ht  = i2 / (64 * L1_KC * 4);
        int g   = nf * NH + ht * 16 + (lam & 15);
        int kb  = kc * 32 + (lam >> 4) * 8;
        f16x8 v;
#pragma unroll
        for (int j = 0; j < 8; ++j) {
            int k = kb + j;
            float val = (k < NH) ? Wih1[(size_t)g * NH + k]
                                 : Whh1[(size_t)g * NH + (k - NH)];
            v[j] = (f16)val;
        }
        f16* dst = (f16*)(ws + W1I_OFF) + (size_t)ht * L1_IMG_HALVES
                 + ((size_t)(nf * L1_KC + kc) * 64 + lam) * 8;
        *(f16x8*)dst = v;
    }
}

// x [B][T][64] fp32 -> xt [T][B][64] fp16 (time-major)
__global__ void prep_x(const float* __restrict__ x, char* __restrict__ ws) {
    int idx = blockIdx.x * 256 + threadIdx.x;          // t*256*8 + b*8 + d8
    if (idx >= NT * NB * 8) return;
    int d8 = idx & 7;
    int b  = (idx >> 3) & 255;
    int t  = idx >> 11;
    const float* src = x + ((size_t)b * NT + t) * NDIN + d8 * 8;
    f16x8 v;
#pragma unroll
    for (int j = 0; j < 8; ++j) v[j] = (f16)src[j];
    f16* dst = (f16*)(ws + XT_OFF) + ((size_t)t * NB + b) * NDIN + d8 * 8;
    *(f16x8*)dst = v;
}

// bias sums + zero flag area + zero h rings (1.5 MB)
__global__ void prep_state(const float* __restrict__ bih0, const float* __restrict__ bhh0,
                           const float* __restrict__ bih1, const float* __restrict__ bhh1,
                           char* __restrict__ ws) {
    int idx = blockIdx.x * 256 + threadIdx.x;
    if (idx < 2048) {
        ((float*)(ws + BIAS0_OFF))[idx] = bih0[idx] + bhh0[idx];
    } else if (idx < 4096) {
        int i = idx - 2048;
        ((float*)(ws + BIAS1_OFF))[i] = bih1[i] + bhh1[i];
    } else {
        int c = idx - 4096;
        uint4 z; z.x = z.y = z.z = z.w = 0u;
        if (c < 512) {                       // 8 KB flag/barrier area
            ((uint4*)(ws + BAR_OFF))[c] = z;
        } else if (c < 512 + 98304) {        // h0 (1 MB) + h1 (512 KB) contiguous
            ((uint4*)(ws + H0R_OFF))[c - 512] = z;
        }
    }
}

// ---------------------------------------------------------------------------
// Persistent kernel helpers
// ---------------------------------------------------------------------------
__device__ __forceinline__ float sigf(float x) { return 1.f / (1.f + __expf(-x)); }
__device__ __forceinline__ float tanhx(float x) { float e = __expf(2.f * x); return 1.f - 2.f / (e + 1.f); }

__device__ __forceinline__ void h_store(f16* p, float v) {
    // relaxed agent sc1 store: write-through to LLC (cross-XCD coherent;
    // disjoint 32B chunks of shared 128B lines merge at LLC).
    unsigned short u = __builtin_bit_cast(unsigned short, (f16)v);
    __hip_atomic_store((unsigned short*)p, u, __ATOMIC_RELAXED, __HIP_MEMORY_SCOPE_AGENT);
}

// 64-lane wave gate on a 32-word flag line (lanes 32-63 mirror words 0-31).
// Ends with a compiler memory barrier so data loads can't hoist above it.
template<int SLP>
__device__ __forceinline__ void gate32(const unsigned* line, unsigned tgt) {
    const int p = threadIdx.x & 31;
    for (;;) {
        unsigned f = __hip_atomic_load(line + p, __ATOMIC_RELAXED, __HIP_MEMORY_SCOPE_AGENT);
        if (__ballot(f < tgt) == 0ULL) break;
        __builtin_amdgcn_s_sleep(SLP);
    }
    asm volatile("" ::: "memory");
}

#define MFMA16(a, b, c) __builtin_amdgcn_mfma_f32_16x16x32_f16((a), (b), (c), 0, 0, 0)

__global__ __launch_bounds__(256, 1) void lstm_persist(char* __restrict__ ws,
                                                       const float* __restrict__ fcW,
                                                       const float* __restrict__ fcb,
                                                       float* __restrict__ out) {
    extern __shared__ __align__(16) char smem[];
    f16*   sW   = (f16*)smem;                 // W image: up to 128 KB
    float* exch = (float*)(smem + 131072);    // 8 KB g/o exchange

    const int tid  = threadIdx.x;
    const int lam  = tid & 63;
    const int w    = tid >> 6;
    const int mh   = w & 1;          // M half (rows b0+mh*32 .. +31)
    const int nh   = w >> 1;         // N half: 0 -> gates i,f ; 1 -> gates g,o
    const int col  = lam & 15;
    const int quad = lam >> 4;

    const int gid   = blockIdx.x & 7;        // group (XCD-aligned heuristic)
    const int layer = gid >> 2;              // 0..1
    const int b0    = (gid & 3) * 64;        // 4 B-tiles of 64
    const int ht    = blockIdx.x >> 3;       // 32 H-tiles of 16
    const int h0c   = ht * 16;
    const int KCx   = layer ? L1_KC : L0_KC;
    const int partner = layer ? (gid - 4) : (gid + 4);

    unsigned* flags    = (unsigned*)(ws + BAR_OFF);
    unsigned* ownline  = flags + (size_t)gid * 32;       // 128 B line per group
    unsigned* partline = flags + (size_t)partner * 32;
    unsigned* myflag   = ownline + ht;

    f16* h0ring = (f16*)(ws + H0R_OFF);
    f16* h1ring = (f16*)(ws + H1R_OFF);
    const f16*   xt   = (const f16*)(ws + XT_OFF);
    const float* bias = (const float*)(ws + (layer ? BIAS1_OFF : BIAS0_OFF));
    const f16*   wimg = (const f16*)(ws + (layer ? W1I_OFF : W0I_OFF))
                      + (size_t)ht * (layer ? L1_IMG_HALVES : L0_IMG_HALVES);

    // Stage this block's W slice into LDS once (lives for all 512 steps).
    {
        const int n16 = KCx * 4 * 64;        // uint4 chunks
        const uint4* src = (const uint4*)wimg;
        uint4* dst = (uint4*)sW;
        for (int i = tid; i < n16; i += 256) dst[i] = src[i];
    }
    __syncthreads();

    const float bi_i = bias[0 * NH + h0c + col];
    const float bi_f = bias[1 * NH + h0c + col];
    const float bi_g = bias[2 * NH + h0c + col];
    const float bi_o = bias[3 * NH + h0c + col];

    float cst[2][4];                          // c state (nh==0 waves)
#pragma unroll
    for (int a = 0; a < 2; ++a)
#pragma unroll
        for (int r = 0; r < 4; ++r) cst[a][r] = 0.f;

    const f16x8* sBf = (const f16x8*)sW;
    const int nf0 = nh * 2, nf1 = nh * 2 + 1;
    const int rA0 = b0 + mh * 32 + col;       // A-row for m-frag 0; +16 for frag 1

    for (int s = 0; s < NT; ++s) {
        const unsigned us = (unsigned)s;
        f32x4 acc00 = {0.f,0.f,0.f,0.f}, acc01 = {0.f,0.f,0.f,0.f};
        f32x4 acc10 = {0.f,0.f,0.f,0.f}, acc11 = {0.f,0.f,0.f,0.f};

        if (layer == 0) {
            // gates: WAR (slack 4, rarely binds) then critical own-recurrence
            if (s >= 4) gate32<8>(partline, us - 3);
            gate32<1>(ownline, us);
            // one L2 inv per wave per step, AFTER gates, BEFORE loads: evicts
            // any stale ring lines planted by ordered-before fetches (ring
            // depth 4/2 + WAR gate makes this airtight); x/W refill is cheap.
            (void)__hip_atomic_load(myflag, __ATOMIC_ACQUIRE, __HIP_MEMORY_SCOPE_AGENT);

            const f16* xa = xt + (size_t)s * NB * NDIN;
            const f16* hp = h0ring + (size_t)((s - 1) & 3) * (NB * NH);   // s=0 -> slot 3 (zeros)
            f16x8 X0[2], X1[2], A0[16], A1[16];
#pragma unroll
            for (int kc = 0; kc < 2; ++kc) {           // x part (K 0..63), L2-warm
                X0[kc] = *(const f16x8*)(xa + (size_t)rA0 * NDIN + kc * 32 + quad * 8);
                X1[kc] = *(const f16x8*)(xa + (size_t)(rA0 + 16) * NDIN + kc * 32 + quad * 8);
            }
#pragma unroll
            for (int kc = 0; kc < 16; ++kc) {          // h0[s-1]: 32 loads in flight
                A0[kc] = *(const f16x8*)(hp + (size_t)rA0 * NH + kc * 32 + quad * 8);
                A1[kc] = *(const f16x8*)(hp + (size_t)(rA0 + 16) * NH + kc * 32 + quad * 8);
            }
#pragma unroll
            for (int kc = 0; kc < L0_KC; ++kc) {
                f16x8 a0 = (kc < 2) ? X0[kc] : A0[kc - 2];
                f16x8 a1 = (kc < 2) ? X1[kc] : A1[kc - 2];
                f16x8 w0 = sBf[(nf0 * L0_KC + kc) * 64 + lam];
                f16x8 w1 = sBf[(nf1 * L0_KC + kc) * 64 + lam];
                acc00 = MFMA16(a0, w0, acc00);
                acc01 = MFMA16(a0, w1, acc01);
                acc10 = MFMA16(a1, w0, acc10);
                acc11 = MFMA16(a1, w1, acc11);
            }
        } else {
            gate32<4>(partline, us + 1);               // h0[s] ready (L0 leads)
            gate32<1>(ownline, us);                    // critical: h1[s-1]
            (void)__hip_atomic_load(myflag, __ATOMIC_ACQUIRE, __HIP_MEMORY_SCOPE_AGENT);

            const f16* hp0 = h0ring + (size_t)(s & 3) * (NB * NH);        // h0[s]
            const f16* hp1 = h1ring + (size_t)((s - 1) & 1) * (NB * NH);  // h1[s-1]
            f16x8 A0[16], A1[16], B0[16], B1[16];
#pragma unroll
            for (int kc = 0; kc < 16; ++kc) {
                A0[kc] = *(const f16x8*)(hp0 + (size_t)rA0 * NH + kc * 32 + quad * 8);
                A1[kc] = *(const f16x8*)(hp0 + (size_t)(rA0 + 16) * NH + kc * 32 + quad * 8);
            }
#pragma unroll
            for (int kc = 0; kc < 16; ++kc) {
                B0[kc] = *(const f16x8*)(hp1 + (size_t)rA0 * NH + kc * 32 + quad * 8);
                B1[kc] = *(const f16x8*)(hp1 + (size_t)(rA0 + 16) * NH + kc * 32 + quad * 8);
            }
#pragma unroll
            for (int kc = 0; kc < L1_KC; ++kc) {
                f16x8 a0 = (kc < 16) ? A0[kc] : B0[kc - 16];
                f16x8 a1 = (kc < 16) ? A1[kc] : B1[kc - 16];
                f16x8 w0 = sBf[(nf0 * L1_KC + kc) * 64 + lam];
                f16x8 w1 = sBf[(nf1 * L1_KC + kc) * 64 + lam];
                acc00 = MFMA16(a0, w0, acc00);
                acc01 = MFMA16(a0, w1, acc01);
                acc10 = MFMA16(a1, w0, acc10);
                acc11 = MFMA16(a1, w1, acc11);
            }
        }

        // g/o waves hand their accs to i/f waves; cell update is register-local there.
        if (nh == 1) {
            f32x4* e4 = (f32x4*)exch;
            e4[((mh * 2 + 0) * 2 + 0) * 64 + lam] = acc00;   // mf0, gate g
            e4[((mh * 2 + 0) * 2 + 1) * 64 + lam] = acc01;   // mf0, gate o
            e4[((mh * 2 + 1) * 2 + 0) * 64 + lam] = acc10;   // mf1, gate g
            e4[((mh * 2 + 1) * 2 + 1) * 64 + lam] = acc11;   // mf1, gate o
        }
        __syncthreads();
        if (nh == 0) {
            const f32x4* e4 = (const f32x4*)exch;
            f32x4 gg0 = e4[((mh * 2 + 0) * 2 + 0) * 64 + lam];
            f32x4 oo0 = e4[((mh * 2 + 0) * 2 + 1) * 64 + lam];
            f32x4 gg1 = e4[((mh * 2 + 1) * 2 + 0) * 64 + lam];
            f32x4 oo1 = e4[((mh * 2 + 1) * 2 + 1) * 64 + lam];
            f16* hw = layer ? (h1ring + (size_t)(s & 1) * (NB * NH))
                            : (h0ring + (size_t)(s & 3) * (NB * NH));
#pragma unroll
            for (int mf = 0; mf < 2; ++mf) {
                f32x4 ai = mf ? acc10 : acc00;
                f32x4 af = mf ? acc11 : acc01;
                f32x4 ag = mf ? gg1 : gg0;
                f32x4 ao = mf ? oo1 : oo0;
#pragma unroll
                for (int r = 0; r < 4; ++r) {
                    float iv = ai[r] + bi_i;
                    float fv = af[r] + bi_f;
                    float gv = ag[r] + bi_g;
                    float ov = ao[r] + bi_o;
                    float cc = sigf(fv) * cst[mf][r] + sigf(iv) * tanhx(gv);
                    cst[mf][r] = cc;
                    float hh = sigf(ov) * tanhx(cc);
                    // C/D layout: row = quad*4 + r, col = lane&15
                    h_store(&hw[(size_t)(b0 + mh * 32 + mf * 16 + quad * 4 + r) * NH + h0c + col], hh);
                }
            }
        }

        // publish: barrier drains all waves' sc1 h-stores (vmcnt(0) before
        // s_barrier), then one relaxed sc1 flag store. No wbl2 needed.
        __syncthreads();
        if (tid == 0)
            __hip_atomic_store(myflag, us + 1, __ATOMIC_RELAXED, __HIP_MEMORY_SCOPE_AGENT);
    }

    // Final FC by block 0: wait for all 4 L1 groups at step NT, then reduce.
    if (blockIdx.x == 0) {
        if (tid < 128) {
            const unsigned* wp = flags + (size_t)(4 + (tid >> 5)) * 32 + (tid & 31);
            while (__hip_atomic_load(wp, __ATOMIC_RELAXED, __HIP_MEMORY_SCOPE_AGENT) < (unsigned)NT)
                __builtin_amdgcn_s_sleep(4);
        }
        __syncthreads();
        if (tid == 0)   // one inv so plain h1 reads below see final LLC data
            (void)__hip_atomic_load(flags, __ATOMIC_ACQUIRE, __HIP_MEMORY_SCOPE_AGENT);
        __syncthreads();
        const f16* hrow = h1ring + (size_t)1 * (NB * NH) + (size_t)tid * NH;  // slot (511)&1 = 1
        float acc = fcb[0];
#pragma unroll 4
        for (int j = 0; j < NH; j += 8) {
            f16x8 hv = *(const f16x8*)(hrow + j);
#pragma unroll
            for (int e = 0; e < 8; ++e) acc += fcW[j + e] * (float)hv[e];
        }
        out[tid] = acc;
    }
}

// ---------------------------------------------------------------------------
extern "C" void kernel_launch(void* const* d_in, const int* in_sizes, int n_in,
                              void* d_out, int out_size, void* d_ws, size_t ws_size,
                              hipStream_t stream) {
    const float* x    = (const float*)d_in[0];
    const float* Wih0 = (const float*)d_in[1];
    const float* Whh0 = (const float*)d_in[2];
    const float* bih0 = (const float*)d_in[3];
    const float* bhh0 = (const float*)d_in[4];
    const float* Wih1 = (const float*)d_in[5];
    const float* Whh1 = (const float*)d_in[6];
    const float* bih1 = (const float*)d_in[7];
    const float* bhh1 = (const float*)d_in[8];
    const float* fcW  = (const float*)d_in[9];
    const float* fcb  = (const float*)d_in[10];
    char*  ws  = (char*)d_ws;
    float* out = (float*)d_out;

    if (ws_size < WS_NEED) {  // deterministic failure instead of corruption
        hipMemsetAsync(d_out, 0, (size_t)out_size * sizeof(float), stream);
        return;
    }

    hipFuncSetAttribute(reinterpret_cast<const void*>(lstm_persist),
                        hipFuncAttributeMaxDynamicSharedMemorySize, 139264);

    prep_weights<<<1600, 256, 0, stream>>>(Wih0, Whh0, Wih1, Whh1, ws);
    prep_x<<<4096, 256, 0, stream>>>(x, ws);
    prep_state<<<402, 256, 0, stream>>>(bih0, bhh0, bih1, bhh1, ws);
    // 256 blocks, 139264 B dynamic LDS -> exactly 1 block/CU on 256 CUs
    lstm_persist<<<256, 256, 139264, stream>>>(ws, fcW, fcb, out);
}

// Round 8
// 7364.334 us; speedup vs baseline: 1.2165x; 1.2165x over previous
//
#include <hip/hip_runtime.h>

// ---------------------------------------------------------------------------
// 2-layer LSTM (B=256,T=512,H=512,DIN=64) + FC, persistent-kernel wavefront.
// R8 = R4 skeleton (proven fastest+stable) + post-consumption invalidate.
//  - detect path: flag polls (parallel waves) -> __syncthreads -> PLAIN loads.
//    No acquire-inv before loads: each block invalidates L1/L2 AFTER consuming
//    (idle nh=1 wave, post-exchange), so at detect time its caches hold no
//    ring lines; every line fetched after a producer's flag is fresh, and
//    peers' plants are same-version (all readers gate on flags; rings rotate
//    inside the straggler window; every block invs every step).
//  - publish stays RELEASE (every relaxed-publish variant R3/R5/R6/R7 showed
//    30-50ms outlier dispatches; R2/R4 release variants never did).
//  - PREF=8 rotation: ~16 loads in flight so the first-toucher block's
//    LLC pass pipelines (group step time is a max over 32 blocks).
// fp16 MFMA (16x16x32), fp32 accum, c-state in registers.
// ---------------------------------------------------------------------------

typedef _Float16 f16;
typedef _Float16 f16x8 __attribute__((ext_vector_type(8)));
typedef float    f32x4 __attribute__((ext_vector_type(4)));
typedef unsigned long long u64;

constexpr int NB   = 256;   // batch
constexpr int NT   = 512;   // time steps
constexpr int NH   = 512;   // hidden
constexpr int NDIN = 64;    // input dim

constexpr int L0_KC = 18;   // K chunks of 32: 64(x) + 512(h0) = 576
constexpr int L1_KC = 32;   // 512(h0) + 512(h1) = 1024
constexpr int L0_IMG_HALVES = 4 * L0_KC * 64 * 8;  // 73728 B per htile
constexpr int L1_IMG_HALVES = 4 * L1_KC * 64 * 8;  // 131072 B per htile

// ws layout (bytes), all 256-aligned (identical to R4)
constexpr size_t BAR_OFF   = 0;                        // flag lines: 8 groups * 128 B
constexpr size_t BIAS0_OFF = 8192;                     // 2048 f32
constexpr size_t BIAS1_OFF = 16384;                    // 2048 f32
constexpr size_t H0R_OFF   = 24576;                    // [4][256][512] f16 = 1 MB
constexpr size_t H1R_OFF   = H0R_OFF + 1048576;        // [2][256][512] f16 = 512 KB
constexpr size_t XT_OFF    = H1R_OFF + 524288;         // [512][256][64] f16
constexpr size_t W0I_OFF   = XT_OFF + 16777216;        // 32 htiles * 73728 B
constexpr size_t W1I_OFF   = W0I_OFF + 2359296;        // 32 htiles * 131072 B
constexpr size_t WS_NEED   = W1I_OFF + 4194304;        // ~23.8 MB

// ---------------------------------------------------------------------------
// Prep: swizzle weights (fp32 -> fp16) into MFMA B-fragment order.
// B-frag layout (16x16x32): lane L holds B[k = (L>>4)*8 + j][n = L&15], j=0..7
// Image element order: [htile][nf(=gate)][kc][lane][8 halves]
// ---------------------------------------------------------------------------
__global__ void prep_weights(const float* __restrict__ Wih0, const float* __restrict__ Whh0,
                             const float* __restrict__ Wih1, const float* __restrict__ Whh1,
                             char* __restrict__ ws) {
    int idx = blockIdx.x * 256 + threadIdx.x;
    const int L0_CH = 32 * 4 * L0_KC * 64;   // 147456
    const int L1_CH = 32 * 4 * L1_KC * 64;   // 262144
    if (idx < L0_CH) {
        int lam = idx & 63;
        int kc  = (idx >> 6) % L0_KC;
        int nf  = ((idx >> 6) / L0_KC) & 3;
        int ht  = idx / (64 * L0_KC * 4);
        int g   = nf * NH + ht * 16 + (lam & 15);   // gate row in [0,2048)
        int kb  = kc * 32 + (lam >> 4) * 8;
        f16x8 v;
#pragma unroll
        for (int j = 0; j < 8; ++j) {
            int k = kb + j;
            float val = (k < NDIN) ? Wih0[(size_t)g * NDIN + k]
                                   : Whh0[(size_t)g * NH + (k - NDIN)];
            v[j] = (f16)val;
        }
        f16* dst = (f16*)(ws + W0I_OFF) + (size_t)ht * L0_IMG_HALVES
                 + ((size_t)(nf * L0_KC + kc) * 64 + lam) * 8;
        *(f16x8*)dst = v;
    } else if (idx < L0_CH + L1_CH) {
        int i2  = idx - L0_CH;
        int lam = i2 & 63;
        int kc  = (i2 >> 6) % L1_KC;
        int nf  = ((i2 >> 6) / L1_KC) & 3;
        int ht  = i2 / (64 * L1_KC * 4);
        int g   = nf * NH + ht * 16 + (lam & 15);
        int kb  = kc * 32 + (lam >> 4) * 8;
        f16x8 v;
#pragma unroll
        for (int j = 0; j < 8; ++j) {
            int k = kb + j;
            float val = (k < NH) ? Wih1[(size_t)g * NH + k]
                                 : Whh1[(size_t)g * NH + (k - NH)];
            v[j] = (f16)val;
        }
        f16* dst = (f16*)(ws + W1I_OFF) + (size_t)ht * L1_IMG_HALVES
                 + ((size_t)(nf * L1_KC + kc) * 64 + lam) * 8;
        *(f16x8*)dst = v;
    }
}

// x [B][T][64] fp32 -> xt [T][B][64] fp16 (time-major)
__global__ void prep_x(const float* __restrict__ x, char* __restrict__ ws) {
    int idx = blockIdx.x * 256 + threadIdx.x;          // t*256*8 + b*8 + d8
    if (idx >= NT * NB * 8) return;
    int d8 = idx & 7;
    int b  = (idx >> 3) & 255;
    int t  = idx >> 11;
    const float* src = x + ((size_t)b * NT + t) * NDIN + d8 * 8;
    f16x8 v;
#pragma unroll
    for (int j = 0; j < 8; ++j) v[j] = (f16)src[j];
    f16* dst = (f16*)(ws + XT_OFF) + ((size_t)t * NB + b) * NDIN + d8 * 8;
    *(f16x8*)dst = v;
}

// bias sums + zero flag area + zero h rings (1.5 MB)
__global__ void prep_state(const float* __restrict__ bih0, const float* __restrict__ bhh0,
                           const float* __restrict__ bih1, const float* __restrict__ bhh1,
                           char* __restrict__ ws) {
    int idx = blockIdx.x * 256 + threadIdx.x;
    if (idx < 2048) {
        ((float*)(ws + BIAS0_OFF))[idx] = bih0[idx] + bhh0[idx];
    } else if (idx < 4096) {
        int i = idx - 2048;
        ((float*)(ws + BIAS1_OFF))[i] = bih1[i] + bhh1[i];
    } else {
        int c = idx - 4096;
        uint4 z; z.x = z.y = z.z = z.w = 0u;
        if (c < 512) {                       // 8 KB flag/barrier area
            ((uint4*)(ws + BAR_OFF))[c] = z;
        } else if (c < 512 + 98304) {        // h0 (1 MB) + h1 (512 KB) contiguous
            ((uint4*)(ws + H0R_OFF))[c - 512] = z;
        }
    }
}

// ---------------------------------------------------------------------------
// Persistent kernel helpers
// ---------------------------------------------------------------------------
__device__ __forceinline__ float sigf(float x) { return 1.f / (1.f + __expf(-x)); }
__device__ __forceinline__ float tanhx(float x) { float e = __expf(2.f * x); return 1.f - 2.f / (e + 1.f); }

__device__ __forceinline__ void h_store(f16* p, float v) {
    // relaxed agent sc1 store: write-through to LLC (cross-XCD coherent;
    // disjoint 32B chunks of shared 128B lines merge at LLC).
    unsigned short u = __builtin_bit_cast(unsigned short, (f16)v);
    __hip_atomic_store((unsigned short*)p, u, __ATOMIC_RELAXED, __HIP_MEMORY_SCOPE_AGENT);
}

template <int SLP>
__device__ __forceinline__ void spin_ge(const unsigned* p, unsigned tgt) {
    while (__hip_atomic_load(p, __ATOMIC_RELAXED, __HIP_MEMORY_SCOPE_AGENT) < tgt)
        __builtin_amdgcn_s_sleep(SLP);
}

#define MFMA16(a, b, c) __builtin_amdgcn_mfma_f32_16x16x32_f16((a), (b), (c), 0, 0, 0)

__global__ __launch_bounds__(256, 1) void lstm_persist(char* __restrict__ ws,
                                                       const float* __restrict__ fcW,
                                                       const float* __restrict__ fcb,
                                                       float* __restrict__ out) {
    extern __shared__ __align__(16) char smem[];
    f16*   sW   = (f16*)smem;                 // W image: up to 128 KB
    float* exch = (float*)(smem + 131072);    // 8 KB g/o exchange

    const int tid  = threadIdx.x;
    const int lam  = tid & 63;
    const int w    = tid >> 6;
    const int mh   = w & 1;          // M half (rows b0+mh*32 .. +31)
    const int nh   = w >> 1;         // N half: 0 -> gates i,f ; 1 -> gates g,o
    const int col  = lam & 15;
    const int quad = lam >> 4;

    const int gid   = blockIdx.x & 7;        // group (XCD-aligned heuristic)
    const int layer = gid >> 2;              // 0..1
    const int b0    = (gid & 3) * 64;        // 4 B-tiles of 64
    const int ht    = blockIdx.x >> 3;       // 32 H-tiles of 16
    const int h0c   = ht * 16;
    const int KCx   = layer ? L1_KC : L0_KC;
    const int partner = layer ? (gid - 4) : (gid + 4);

    unsigned* flags    = (unsigned*)(ws + BAR_OFF);
    unsigned* ownline  = flags + (size_t)gid * 32;       // 128 B line per group
    unsigned* partline = flags + (size_t)partner * 32;
    unsigned* myflag   = ownline + ht;

    f16* h0ring = (f16*)(ws + H0R_OFF);
    f16* h1ring = (f16*)(ws + H1R_OFF);
    const f16*   xt   = (const f16*)(ws + XT_OFF);
    const float* bias = (const float*)(ws + (layer ? BIAS1_OFF : BIAS0_OFF));
    const f16*   wimg = (const f16*)(ws + (layer ? W1I_OFF : W0I_OFF))
                      + (size_t)ht * (layer ? L1_IMG_HALVES : L0_IMG_HALVES);

    // Stage this block's W slice into LDS once (lives for all 512 steps).
    {
        const int n16 = KCx * 4 * 64;        // uint4 chunks
        const uint4* src = (const uint4*)wimg;
        uint4* dst = (uint4*)sW;
        for (int i = tid; i < n16; i += 256) dst[i] = src[i];
    }
    __syncthreads();

    const float bi_i = bias[0 * NH + h0c + col];
    const float bi_f = bias[1 * NH + h0c + col];
    const float bi_g = bias[2 * NH + h0c + col];
    const float bi_o = bias[3 * NH + h0c + col];

    float cst[2][4];                          // c state (nh==0 waves)
#pragma unroll
    for (int a = 0; a < 2; ++a)
#pragma unroll
        for (int r = 0; r < 4; ++r) cst[a][r] = 0.f;

    const f16x8* sBf = (const f16x8*)sW;
    const int nf0 = nh * 2, nf1 = nh * 2 + 1;
    const int rA0 = b0 + mh * 32 + col;       // A-row for m-frag 0; +16 for frag 1
    constexpr int PREF = 8;                   // ~16 loads in flight per wave

    for (int s = 0; s < NT; ++s) {
        const unsigned us = (unsigned)s;

        // ---- dependency polls (parallel: different waves poll different lines)
        if (layer == 0) {
            if (tid < 32 && s > 0) spin_ge<1>(ownline + tid, us);               // critical
            if (tid >= 64 && tid < 96 && s >= 4) spin_ge<8>(partline + (tid - 64), us - 3);  // WAR
        } else {
            if (tid < 32) spin_ge<2>(partline + tid, us + 1);                   // h0[s] (L0 leads)
            if (tid >= 64 && tid < 96 && s > 0) spin_ge<1>(ownline + (tid - 64), us);        // critical
        }
        __syncthreads();
        // NO acquire here: post-consumption inv (below) guarantees our L1/L2
        // hold no ring lines at this point; all plants are post-flag = fresh.

        // ---- gate GEMM (plain loads: L2-served broadcast across the group) ----
        f32x4 acc00 = {0.f,0.f,0.f,0.f}, acc01 = {0.f,0.f,0.f,0.f};
        f32x4 acc10 = {0.f,0.f,0.f,0.f}, acc11 = {0.f,0.f,0.f,0.f};

        if (layer == 0) {
            const f16* xa = xt + (size_t)s * NB * NDIN;
            const f16* hp = h0ring + (size_t)((s - 1) & 3) * (NB * NH);   // s=0 -> slot 3 (zeros)
            auto ldA0 = [&](int kc) -> f16x8 {
                return (kc < 2) ? *(const f16x8*)(xa + (size_t)rA0 * NDIN + kc * 32 + quad * 8)
                                : *(const f16x8*)(hp + (size_t)rA0 * NH + (kc - 2) * 32 + quad * 8);
            };
            auto ldA1 = [&](int kc) -> f16x8 {
                return (kc < 2) ? *(const f16x8*)(xa + (size_t)(rA0 + 16) * NDIN + kc * 32 + quad * 8)
                                : *(const f16x8*)(hp + (size_t)(rA0 + 16) * NH + (kc - 2) * 32 + quad * 8);
            };
            f16x8 pa[PREF], pb[PREF];
#pragma unroll
            for (int p = 0; p < PREF; ++p) { pa[p] = ldA0(p); pb[p] = ldA1(p); }
#pragma unroll
            for (int kc = 0; kc < L0_KC; ++kc) {
                f16x8 a0 = pa[kc & (PREF - 1)], a1 = pb[kc & (PREF - 1)];
                if (kc + PREF < L0_KC) { pa[kc & (PREF - 1)] = ldA0(kc + PREF); pb[kc & (PREF - 1)] = ldA1(kc + PREF); }
                f16x8 w0 = sBf[(nf0 * L0_KC + kc) * 64 + lam];
                f16x8 w1 = sBf[(nf1 * L0_KC + kc) * 64 + lam];
                acc00 = MFMA16(a0, w0, acc00);
                acc01 = MFMA16(a0, w1, acc01);
                acc10 = MFMA16(a1, w0, acc10);
                acc11 = MFMA16(a1, w1, acc11);
            }
        } else {
            const f16* hp0 = h0ring + (size_t)(s & 3) * (NB * NH);        // h0[s]
            const f16* hp1 = h1ring + (size_t)((s - 1) & 1) * (NB * NH);  // h1[s-1]
            auto ldA0 = [&](int kc) -> f16x8 {
                return (kc < 16) ? *(const f16x8*)(hp0 + (size_t)rA0 * NH + kc * 32 + quad * 8)
                                 : *(const f16x8*)(hp1 + (size_t)rA0 * NH + (kc - 16) * 32 + quad * 8);
            };
            auto ldA1 = [&](int kc) -> f16x8 {
                return (kc < 16) ? *(const f16x8*)(hp0 + (size_t)(rA0 + 16) * NH + kc * 32 + quad * 8)
                                 : *(const f16x8*)(hp1 + (size_t)(rA0 + 16) * NH + (kc - 16) * 32 + quad * 8);
            };
            f16x8 pa[PREF], pb[PREF];
#pragma unroll
            for (int p = 0; p < PREF; ++p) { pa[p] = ldA0(p); pb[p] = ldA1(p); }
#pragma unroll
            for (int kc = 0; kc < L1_KC; ++kc) {
                f16x8 a0 = pa[kc & (PREF - 1)], a1 = pb[kc & (PREF - 1)];
                if (kc + PREF < L1_KC) { pa[kc & (PREF - 1)] = ldA0(kc + PREF); pb[kc & (PREF - 1)] = ldA1(kc + PREF); }
                f16x8 w0 = sBf[(nf0 * L1_KC + kc) * 64 + lam];
                f16x8 w1 = sBf[(nf1 * L1_KC + kc) * 64 + lam];
                acc00 = MFMA16(a0, w0, acc00);
                acc01 = MFMA16(a0, w1, acc01);
                acc10 = MFMA16(a1, w0, acc10);
                acc11 = MFMA16(a1, w1, acc11);
            }
        }

        // g/o waves hand their accs to i/f waves; cell update is register-local there.
        if (nh == 1) {
            f32x4* e4 = (f32x4*)exch;
            e4[((mh * 2 + 0) * 2 + 0) * 64 + lam] = acc00;   // mf0, gate g
            e4[((mh * 2 + 0) * 2 + 1) * 64 + lam] = acc01;   // mf0, gate o
            e4[((mh * 2 + 1) * 2 + 0) * 64 + lam] = acc10;   // mf1, gate g
            e4[((mh * 2 + 1) * 2 + 1) * 64 + lam] = acc11;   // mf1, gate o
        }
        __syncthreads();   // all waves' A-loads consumed beyond this point

        // ---- post-consumption invalidate (idle nh=1 wave, OFF critical path):
        // evicts this step's ring lines from our L1+L2 before the next write of
        // those slots; lands before peers' next fetch window -> no destruction.
        if (tid == 128)
            (void)__hip_atomic_load(myflag, __ATOMIC_ACQUIRE, __HIP_MEMORY_SCOPE_AGENT);

        if (nh == 0) {
            const f32x4* e4 = (const f32x4*)exch;
            f32x4 gg0 = e4[((mh * 2 + 0) * 2 + 0) * 64 + lam];
            f32x4 oo0 = e4[((mh * 2 + 0) * 2 + 1) * 64 + lam];
            f32x4 gg1 = e4[((mh * 2 + 1) * 2 + 0) * 64 + lam];
            f32x4 oo1 = e4[((mh * 2 + 1) * 2 + 1) * 64 + lam];
            f16* hw = layer ? (h1ring + (size_t)(s & 1) * (NB * NH))
                            : (h0ring + (size_t)(s & 3) * (NB * NH));
#pragma unroll
            for (int mf = 0; mf < 2; ++mf) {
                f32x4 ai = mf ? acc10 : acc00;
                f32x4 af = mf ? acc11 : acc01;
                f32x4 ag = mf ? gg1 : gg0;
                f32x4 ao = mf ? oo1 : oo0;
#pragma unroll
                for (int r = 0; r < 4; ++r) {
                    float iv = ai[r] + bi_i;
                    float fv = af[r] + bi_f;
                    float gv = ag[r] + bi_g;
                    float ov = ao[r] + bi_o;
                    float cc = sigf(fv) * cst[mf][r] + sigf(iv) * tanhx(gv);
                    cst[mf][r] = cc;
                    float hh = sigf(ov) * tanhx(cc);
                    // C/D layout: row = quad*4 + r, col = lane&15
                    h_store(&hw[(size_t)(b0 + mh * 32 + mf * 16 + quad * 4 + r) * NH + h0c + col], hh);
                }
            }
        }

        // ---- publish: barrier drains all waves' sc1 h-stores (vmcnt(0) before
        // s_barrier), then one RELEASE flag store (empirically outlier-free).
        __syncthreads();
        if (tid == 0)
            __hip_atomic_store(myflag, us + 1, __ATOMIC_RELEASE, __HIP_MEMORY_SCOPE_AGENT);
    }

    // Final FC by block 0: wait for all 4 L1 groups at step NT, then reduce.
    if (blockIdx.x == 0) {
        if (tid < 128) {
            const unsigned* wp = flags + (size_t)(4 + (tid >> 5)) * 32 + (tid & 31);
            while (__hip_atomic_load(wp, __ATOMIC_RELAXED, __HIP_MEMORY_SCOPE_AGENT) < (unsigned)NT)
                __builtin_amdgcn_s_sleep(4);
        }
        __syncthreads();
        if (tid == 0)   // one inv so plain h1 reads below see final LLC data
            (void)__hip_atomic_load(flags, __ATOMIC_ACQUIRE, __HIP_MEMORY_SCOPE_AGENT);
        __syncthreads();
        const f16* hrow = h1ring + (size_t)1 * (NB * NH) + (size_t)tid * NH;  // slot (511)&1 = 1
        float acc = fcb[0];
#pragma unroll 4
        for (int j = 0; j < NH; j += 8) {
            f16x8 hv = *(const f16x8*)(hrow + j);
#pragma unroll
            for (int e = 0; e < 8; ++e) acc += fcW[j + e] * (float)hv[e];
        }
        out[tid] = acc;
    }
}

// ---------------------------------------------------------------------------
extern "C" void kernel_launch(void* const* d_in, const int* in_sizes, int n_in,
                              void* d_out, int out_size, void* d_ws, size_t ws_size,
                              hipStream_t stream) {
    const float* x    = (const float*)d_in[0];
    const float* Wih0 = (const float*)d_in[1];
    const float* Whh0 = (const float*)d_in[2];
    const float* bih0 = (const float*)d_in[3];
    const float* bhh0 = (const float*)d_in[4];
    const float* Wih1 = (const float*)d_in[5];
    const float* Whh1 = (const float*)d_in[6];
    const float* bih1 = (const float*)d_in[7];
    const float* bhh1 = (const float*)d_in[8];
    const float* fcW  = (const float*)d_in[9];
    const float* fcb  = (const float*)d_in[10];
    char*  ws  = (char*)d_ws;
    float* out = (float*)d_out;

    if (ws_size < WS_NEED) {  // deterministic failure instead of corruption
        hipMemsetAsync(d_out, 0, (size_t)out_size * sizeof(float), stream);
        return;
    }

    hipFuncSetAttribute(reinterpret_cast<const void*>(lstm_persist),
                        hipFuncAttributeMaxDynamicSharedMemorySize, 139264);

    prep_weights<<<1600, 256, 0, stream>>>(Wih0, Whh0, Wih1, Whh1, ws);
    prep_x<<<4096, 256, 0, stream>>>(x, ws);
    prep_state<<<402, 256, 0, stream>>>(bih0, bhh0, bih1, bhh1, ws);
    // 256 blocks, 139264 B dynamic LDS -> exactly 1 block/CU on 256 CUs
    lstm_persist<<<256, 256, 139264, stream>>>(ws, fcW, fcb, out);
}

// Round 9
// 6342.524 us; speedup vs baseline: 1.4125x; 1.1611x over previous
//
#include <hip/hip_runtime.h>

// ---------------------------------------------------------------------------
// 2-layer LSTM (B=256,T=512,H=512,DIN=64) + FC, persistent-kernel wavefront.
// R9: RMW-based sync + address-rotated rings (staleness-proof by construction).
//  Model (from 8 rounds of evidence): RELAXED agent loads/stores are served by
//  the local XCD L2 -> flag visibility rides L2 eviction (~10us, topology-
//  invariant floor; metastable outliers when publishes are relaxed). Atomic
//  RMWs at agent scope MUST execute at the LLC -> always fresh.
//   - publish: one fetch_add(+1, RELEASE) per block-step on cnt[group][slot]
//     (release wbl2 also flushes h-data to LLC under any store semantics).
//   - detect: single-lane fetch_add(+0, RELAXED) poll of the counter.
//   - data: PLAIN loads (L2-served 32-way broadcast; R5 showed LLC-direct
//     reads are BW-infeasible), safe via depth-8 ring rotation + one
//     acquire-inv per block every 8 steps (phase-spread by ht).
//   - x read directly from d_in (xt prep dropped) -> ws ~15MB.
// fp16 MFMA (16x16x32), fp32 accum, c-state in registers.
// ---------------------------------------------------------------------------

typedef _Float16 f16;
typedef _Float16 f16x8 __attribute__((ext_vector_type(8)));
typedef float    f32x4 __attribute__((ext_vector_type(4)));

constexpr int NB   = 256;   // batch
constexpr int NT   = 512;   // time steps
constexpr int NH   = 512;   // hidden
constexpr int NDIN = 64;    // input dim

constexpr int L0_KC = 18;   // K chunks of 32: 64(x) + 512(h0) = 576
constexpr int L1_KC = 32;   // 512(h0) + 512(h1) = 1024
constexpr int L0_IMG_HALVES = 4 * L0_KC * 64 * 8;  // 73728 B per htile
constexpr int L1_IMG_HALVES = 4 * L1_KC * 64 * 8;  // 131072 B per htile

constexpr int RING = 8;     // ring depth (address rotation period)

// ws layout (bytes), all 256-aligned
constexpr size_t BAR_OFF   = 0;                        // cnt[slot][group]: 64 lines * 128 B
constexpr size_t BIAS0_OFF = 8192;                     // 2048 f32
constexpr size_t BIAS1_OFF = 16384;                    // 2048 f32
constexpr size_t H0R_OFF   = 24576;                    // [8][256][512] f16 = 2 MB... (RING*256KB=2MB? no: 8*256*512*2B = 2MB) actually 8 slots x 256x512x2B = 2 MB
constexpr size_t H1R_OFF   = H0R_OFF + (size_t)RING * NB * NH * 2;   // + 2MB
constexpr size_t W0I_OFF   = H1R_OFF + (size_t)RING * NB * NH * 2;   // + 2MB
constexpr size_t W1I_OFF   = W0I_OFF + 2359296;        // 32 htiles * 73728 B
constexpr size_t WS_NEED   = W1I_OFF + 4194304;        // ~10.9 MB

// ---------------------------------------------------------------------------
// Prep: swizzle weights (fp32 -> fp16) into MFMA B-fragment order.
// B-frag layout (16x16x32): lane L holds B[k = (L>>4)*8 + j][n = L&15], j=0..7
// Image element order: [htile][nf(=gate)][kc][lane][8 halves]
// ---------------------------------------------------------------------------
__global__ void prep_weights(const float* __restrict__ Wih0, const float* __restrict__ Whh0,
                             const float* __restrict__ Wih1, const float* __restrict__ Whh1,
                             char* __restrict__ ws) {
    int idx = blockIdx.x * 256 + threadIdx.x;
    const int L0_CH = 32 * 4 * L0_KC * 64;   // 147456
    const int L1_CH = 32 * 4 * L1_KC * 64;   // 262144
    if (idx < L0_CH) {
        int lam = idx & 63;
        int kc  = (idx >> 6) % L0_KC;
        int nf  = ((idx >> 6) / L0_KC) & 3;
        int ht  = idx / (64 * L0_KC * 4);
        int g   = nf * NH + ht * 16 + (lam & 15);   // gate row in [0,2048)
        int kb  = kc * 32 + (lam >> 4) * 8;
        f16x8 v;
#pragma unroll
        for (int j = 0; j < 8; ++j) {
            int k = kb + j;
            float val = (k < NDIN) ? Wih0[(size_t)g * NDIN + k]
                                   : Whh0[(size_t)g * NH + (k - NDIN)];
            v[j] = (f16)val;
        }
        f16* dst = (f16*)(ws + W0I_OFF) + (size_t)ht * L0_IMG_HALVES
                 + ((size_t)(nf * L0_KC + kc) * 64 + lam) * 8;
        *(f16x8*)dst = v;
    } else if (idx < L0_CH + L1_CH) {
        int i2  = idx - L0_CH;
        int lam = i2 & 63;
        int kc  = (i2 >> 6) % L1_KC;
        int nf  = ((i2 >> 6) / L1_KC) & 3;
        int ht  = i2 / (64 * L1_KC * 4);
        int g   = nf * NH + ht * 16 + (lam & 15);
        int kb  = kc * 32 + (lam >> 4) * 8;
        f16x8 v;
#pragma unroll
        for (int j = 0; j < 8; ++j) {
            int k = kb + j;
            float val = (k < NH) ? Wih1[(size_t)g * NH + k]
                                 : Whh1[(size_t)g * NH + (k - NH)];
            v[j] = (f16)val;
        }
        f16* dst = (f16*)(ws + W1I_OFF) + (size_t)ht * L1_IMG_HALVES
                 + ((size_t)(nf * L1_KC + kc) * 64 + lam) * 8;
        *(f16x8*)dst = v;
    }
}

// bias sums + zero counter area + zero both h rings (4 MB)
__global__ void prep_state(const float* __restrict__ bih0, const float* __restrict__ bhh0,
                           const float* __restrict__ bih1, const float* __restrict__ bhh1,
                           char* __restrict__ ws) {
    int idx = blockIdx.x * 256 + threadIdx.x;
    const int RINGU4 = (int)((size_t)2 * RING * NB * NH * 2 / 16);   // 262144
    if (idx < 2048) {
        ((float*)(ws + BIAS0_OFF))[idx] = bih0[idx] + bhh0[idx];
    } else if (idx < 4096) {
        int i = idx - 2048;
        ((float*)(ws + BIAS1_OFF))[i] = bih1[i] + bhh1[i];
    } else {
        int c = idx - 4096;
        uint4 z; z.x = z.y = z.z = z.w = 0u;
        if (c < 512) {                       // 8 KB counter area
            ((uint4*)(ws + BAR_OFF))[c] = z;
        } else if (c < 512 + RINGU4) {       // h0 + h1 rings contiguous
            ((uint4*)(ws + H0R_OFF))[c - 512] = z;
        }
    }
}

// ---------------------------------------------------------------------------
// Persistent kernel helpers
// ---------------------------------------------------------------------------
__device__ __forceinline__ float sigf(float x) { return 1.f / (1.f + __expf(-x)); }
__device__ __forceinline__ float tanhx(float x) { float e = __expf(2.f * x); return 1.f - 2.f / (e + 1.f); }

__device__ __forceinline__ void h_store(f16* p, float v) {
    unsigned short u = __builtin_bit_cast(unsigned short, (f16)v);
    __hip_atomic_store((unsigned short*)p, u, __ATOMIC_RELAXED, __HIP_MEMORY_SCOPE_AGENT);
}

// RMW poll: executes at the LLC (agent-scope atomicity) -> never stale.
template <int SLP>
__device__ __forceinline__ void spin_cnt(unsigned* p, unsigned tgt) {
    while (__hip_atomic_fetch_add(p, 0u, __ATOMIC_RELAXED, __HIP_MEMORY_SCOPE_AGENT) < tgt)
        __builtin_amdgcn_s_sleep(SLP);
}

#define MFMA16(a, b, c) __builtin_amdgcn_mfma_f32_16x16x32_f16((a), (b), (c), 0, 0, 0)

__global__ __launch_bounds__(256, 1) void lstm_persist(char* __restrict__ ws,
                                                       const float* __restrict__ xin,
                                                       const float* __restrict__ fcW,
                                                       const float* __restrict__ fcb,
                                                       float* __restrict__ out) {
    extern __shared__ __align__(16) char smem[];
    f16*   sW   = (f16*)smem;                 // W image: up to 128 KB
    float* exch = (float*)(smem + 131072);    // 8 KB g/o exchange

    const int tid  = threadIdx.x;
    const int lam  = tid & 63;
    const int w    = tid >> 6;
    const int mh   = w & 1;          // M half (rows b0+mh*32 .. +31)
    const int nh   = w >> 1;         // N half: 0 -> gates i,f ; 1 -> gates g,o
    const int col  = lam & 15;
    const int quad = lam >> 4;

    const int gid   = blockIdx.x & 7;        // group (XCD-aligned heuristic)
    const int layer = gid >> 2;              // 0..1
    const int b0    = (gid & 3) * 64;        // 4 B-tiles of 64
    const int ht    = blockIdx.x >> 3;       // 32 H-tiles of 16
    const int h0c   = ht * 16;
    const int KCx   = layer ? L1_KC : L0_KC;

    // cnt line for (group g, ring slot k): one 128B line each
    auto cntp = [&](int g, int slot) -> unsigned* {
        return (unsigned*)(ws + BAR_OFF + (size_t)(slot * 8 + g) * 128);
    };

    f16* h0ring = (f16*)(ws + H0R_OFF);
    f16* h1ring = (f16*)(ws + H1R_OFF);
    const float* bias = (const float*)(ws + (layer ? BIAS1_OFF : BIAS0_OFF));
    const f16*   wimg = (const f16*)(ws + (layer ? W1I_OFF : W0I_OFF))
                      + (size_t)ht * (layer ? L1_IMG_HALVES : L0_IMG_HALVES);

    // Stage this block's W slice into LDS once (lives for all 512 steps).
    {
        const int n16 = KCx * 4 * 64;        // uint4 chunks
        const uint4* src = (const uint4*)wimg;
        uint4* dst = (uint4*)sW;
        for (int i = tid; i < n16; i += 256) dst[i] = src[i];
    }
    __syncthreads();

    const float bi_i = bias[0 * NH + h0c + col];
    const float bi_f = bias[1 * NH + h0c + col];
    const float bi_g = bias[2 * NH + h0c + col];
    const float bi_o = bias[3 * NH + h0c + col];

    float cst[2][4];                          // c state (nh==0 waves)
#pragma unroll
    for (int a = 0; a < 2; ++a)
#pragma unroll
        for (int r = 0; r < 4; ++r) cst[a][r] = 0.f;

    const f16x8* sBf = (const f16x8*)sW;
    const int nf0 = nh * 2, nf1 = nh * 2 + 1;
    const int rA0 = b0 + mh * 32 + col;       // A-row for m-frag 0; +16 for frag 1
    constexpr int PREF = 8;

    for (int s = 0; s < NT; ++s) {
        const unsigned us = (unsigned)s;

        // ---- dependency polls (single-lane RMW; always LLC-fresh) ----
        if (layer == 0) {
            // critical: own group done step s-1 (h0[s-1] complete at LLC)
            if (tid == 0 && s > 0)
                spin_cnt<1>(cntp(gid, (s - 1) & 7), 32u * (((us - 1) >> 3) + 1));
            // WAR (slack 8): L1 partner done step s-8 (we overwrite h0 slot s&7)
            if (tid == 64 && s >= RING)
                spin_cnt<8>(cntp(gid + 4, s & 7), 32u * (us >> 3));
        } else {
            // critical: own group done step s-1 (h1[s-1])
            if (tid == 0 && s > 0)
                spin_cnt<1>(cntp(gid, (s - 1) & 7), 32u * (((us - 1) >> 3) + 1));
            // L0 partner done step s (h0[s] ready; L0 leads so this has slack)
            if (tid == 64)
                spin_cnt<4>(cntp(gid - 4, s & 7), 32u * ((us >> 3) + 1));
        }
        __syncthreads();

        // ---- gate GEMM (PLAIN loads; slot addresses unseen for 8 steps ->
        // compulsory L2 miss -> fresh from LLC, then L2-served broadcast) ----
        f32x4 acc00 = {0.f,0.f,0.f,0.f}, acc01 = {0.f,0.f,0.f,0.f};
        f32x4 acc10 = {0.f,0.f,0.f,0.f}, acc11 = {0.f,0.f,0.f,0.f};

        if (layer == 0) {
            const f16* hp = h0ring + (size_t)((s - 1) & 7) * (NB * NH);   // s=0 -> slot 7 (zeros)
            auto ldX = [&](int row, int kc) -> f16x8 {
                const float* xr = xin + (size_t)row * (NT * NDIN) + (size_t)s * NDIN + kc * 32 + quad * 8;
                float4 f0 = *(const float4*)xr;
                float4 f1 = *(const float4*)(xr + 4);
                f16x8 v;
                v[0] = (f16)f0.x; v[1] = (f16)f0.y; v[2] = (f16)f0.z; v[3] = (f16)f0.w;
                v[4] = (f16)f1.x; v[5] = (f16)f1.y; v[6] = (f16)f1.z; v[7] = (f16)f1.w;
                return v;
            };
            auto ldA0 = [&](int kc) -> f16x8 {
                return (kc < 2) ? ldX(rA0, kc)
                                : *(const f16x8*)(hp + (size_t)rA0 * NH + (kc - 2) * 32 + quad * 8);
            };
            auto ldA1 = [&](int kc) -> f16x8 {
                return (kc < 2) ? ldX(rA0 + 16, kc)
                                : *(const f16x8*)(hp + (size_t)(rA0 + 16) * NH + (kc - 2) * 32 + quad * 8);
            };
            f16x8 pa[PREF], pb[PREF];
#pragma unroll
            for (int p = 0; p < PREF; ++p) { pa[p] = ldA0(p); pb[p] = ldA1(p); }
#pragma unroll
            for (int kc = 0; kc < L0_KC; ++kc) {
                f16x8 a0 = pa[kc & (PREF - 1)], a1 = pb[kc & (PREF - 1)];
                if (kc + PREF < L0_KC) { pa[kc & (PREF - 1)] = ldA0(kc + PREF); pb[kc & (PREF - 1)] = ldA1(kc + PREF); }
                f16x8 w0 = sBf[(nf0 * L0_KC + kc) * 64 + lam];
                f16x8 w1 = sBf[(nf1 * L0_KC + kc) * 64 + lam];
                acc00 = MFMA16(a0, w0, acc00);
                acc01 = MFMA16(a0, w1, acc01);
                acc10 = MFMA16(a1, w0, acc10);
                acc11 = MFMA16(a1, w1, acc11);
            }
        } else {
            const f16* hp0 = h0ring + (size_t)(s & 7) * (NB * NH);        // h0[s]
            const f16* hp1 = h1ring + (size_t)((s - 1) & 7) * (NB * NH);  // h1[s-1]; s=0 -> slot 7 (zeros)
            auto ldA0 = [&](int kc) -> f16x8 {
                return (kc < 16) ? *(const f16x8*)(hp0 + (size_t)rA0 * NH + kc * 32 + quad * 8)
                                 : *(const f16x8*)(hp1 + (size_t)rA0 * NH + (kc - 16) * 32 + quad * 8);
            };
            auto ldA1 = [&](int kc) -> f16x8 {
                return (kc < 16) ? *(const f16x8*)(hp0 + (size_t)(rA0 + 16) * NH + kc * 32 + quad * 8)
                                 : *(const f16x8*)(hp1 + (size_t)(rA0 + 16) * NH + (kc - 16) * 32 + quad * 8);
            };
            f16x8 pa[PREF], pb[PREF];
#pragma unroll
            for (int p = 0; p < PREF; ++p) { pa[p] = ldA0(p); pb[p] = ldA1(p); }
#pragma unroll
            for (int kc = 0; kc < L1_KC; ++kc) {
                f16x8 a0 = pa[kc & (PREF - 1)], a1 = pb[kc & (PREF - 1)];
                if (kc + PREF < L1_KC) { pa[kc & (PREF - 1)] = ldA0(kc + PREF); pb[kc & (PREF - 1)] = ldA1(kc + PREF); }
                f16x8 w0 = sBf[(nf0 * L1_KC + kc) * 64 + lam];
                f16x8 w1 = sBf[(nf1 * L1_KC + kc) * 64 + lam];
                acc00 = MFMA16(a0, w0, acc00);
                acc01 = MFMA16(a0, w1, acc01);
                acc10 = MFMA16(a1, w0, acc10);
                acc11 = MFMA16(a1, w1, acc11);
            }
        }

        // g/o waves hand their accs to i/f waves; cell update is register-local there.
        if (nh == 1) {
            f32x4* e4 = (f32x4*)exch;
            e4[((mh * 2 + 0) * 2 + 0) * 64 + lam] = acc00;   // mf0, gate g
            e4[((mh * 2 + 0) * 2 + 1) * 64 + lam] = acc01;   // mf0, gate o
            e4[((mh * 2 + 1) * 2 + 0) * 64 + lam] = acc10;   // mf1, gate g
            e4[((mh * 2 + 1) * 2 + 1) * 64 + lam] = acc11;   // mf1, gate o
        }
        __syncthreads();   // all waves' A-loads consumed beyond this point

        // ---- staleness bound: one acquire-inv per block every RING steps,
        // phase-spread by ht, post-consumption (off the critical detect path).
        // Guarantees: any ring line we cached >= 8 steps ago is evicted before
        // that slot's addresses are re-consumed.
        if (tid == 128 && ((s & 7) == (ht & 7)))
            (void)__hip_atomic_load((unsigned*)(ws + BAR_OFF), __ATOMIC_ACQUIRE, __HIP_MEMORY_SCOPE_AGENT);

        if (nh == 0) {
            const f32x4* e4 = (const f32x4*)exch;
            f32x4 gg0 = e4[((mh * 2 + 0) * 2 + 0) * 64 + lam];
            f32x4 oo0 = e4[((mh * 2 + 0) * 2 + 1) * 64 + lam];
            f32x4 gg1 = e4[((mh * 2 + 1) * 2 + 0) * 64 + lam];
            f32x4 oo1 = e4[((mh * 2 + 1) * 2 + 1) * 64 + lam];
            f16* hw = (layer ? h1ring : h0ring) + (size_t)(s & 7) * (NB * NH);
#pragma unroll
            for (int mf = 0; mf < 2; ++mf) {
                f32x4 ai = mf ? acc10 : acc00;
                f32x4 af = mf ? acc11 : acc01;
                f32x4 ag = mf ? gg1 : gg0;
                f32x4 ao = mf ? oo1 : oo0;
#pragma unroll
                for (int r = 0; r < 4; ++r) {
                    float iv = ai[r] + bi_i;
                    float fv = af[r] + bi_f;
                    float gv = ag[r] + bi_g;
                    float ov = ao[r] + bi_o;
                    float cc = sigf(fv) * cst[mf][r] + sigf(iv) * tanhx(gv);
                    cst[mf][r] = cc;
                    float hh = sigf(ov) * tanhx(cc);
                    // C/D layout: row = quad*4 + r, col = lane&15
                    h_store(&hw[(size_t)(b0 + mh * 32 + mf * 16 + quad * 4 + r) * NH + h0c + col], hh);
                }
            }
        }

        // ---- publish: barrier drains all h-stores (vmcnt(0) before s_barrier),
        // then ONE release fetch_add: wbl2 flushes any dirty h lines to LLC,
        // the add lands at the LLC (never stale for RMW-pollers).
        __syncthreads();
        if (tid == 0)
            __hip_atomic_fetch_add(cntp(gid, s & 7), 1u, __ATOMIC_RELEASE, __HIP_MEMORY_SCOPE_AGENT);
    }

    // Final FC by block 0: all 4 L1 groups must complete step 511 (slot 7, rot 63).
    if (blockIdx.x == 0) {
        if (tid < 4)
            spin_cnt<4>(cntp(4 + tid, 7), 32u * 64u);
        __syncthreads();
        if (tid == 0)
            (void)__hip_atomic_load((unsigned*)(ws + BAR_OFF), __ATOMIC_ACQUIRE, __HIP_MEMORY_SCOPE_AGENT);
        __syncthreads();
        const f16* hrow = h1ring + (size_t)7 * (NB * NH) + (size_t)tid * NH;  // slot 511&7 = 7
        float acc = fcb[0];
#pragma unroll 4
        for (int j = 0; j < NH; j += 8) {
            f16x8 hv = *(const f16x8*)(hrow + j);
#pragma unroll
            for (int e = 0; e < 8; ++e) acc += fcW[j + e] * (float)hv[e];
        }
        out[tid] = acc;
    }
}

// ---------------------------------------------------------------------------
extern "C" void kernel_launch(void* const* d_in, const int* in_sizes, int n_in,
                              void* d_out, int out_size, void* d_ws, size_t ws_size,
                              hipStream_t stream) {
    const float* x    = (const float*)d_in[0];
    const float* Wih0 = (const float*)d_in[1];
    const float* Whh0 = (const float*)d_in[2];
    const float* bih0 = (const float*)d_in[3];
    const float* bhh0 = (const float*)d_in[4];
    const float* Wih1 = (const float*)d_in[5];
    const float* Whh1 = (const float*)d_in[6];
    const float* bih1 = (const float*)d_in[7];
    const float* bhh1 = (const float*)d_in[8];
    const float* fcW  = (const float*)d_in[9];
    const float* fcb  = (const float*)d_in[10];
    char*  ws  = (char*)d_ws;
    float* out = (float*)d_out;

    if (ws_size < WS_NEED) {  // deterministic failure instead of corruption
        hipMemsetAsync(d_out, 0, (size_t)out_size * sizeof(float), stream);
        return;
    }

    hipFuncSetAttribute(reinterpret_cast<const void*>(lstm_persist),
                        hipFuncAttributeMaxDynamicSharedMemorySize, 139264);

    prep_weights<<<1600, 256, 0, stream>>>(Wih0, Whh0, Wih1, Whh1, ws);
    prep_state<<<1100, 256, 0, stream>>>(bih0, bhh0, bih1, bhh1, ws);
    // 256 blocks, 139264 B dynamic LDS -> exactly 1 block/CU on 256 CUs
    lstm_persist<<<256, 256, 139264, stream>>>(ws, x, fcW, fcb, out);
}